// Round 1
// 858.709 us; speedup vs baseline: 1.3280x; 1.3280x over previous
//
#include <hip/hip_runtime.h>

#define A_DIM 64
#define B_DIM 128
#define E 128
#define NG 50
#define NROW (A_DIM*A_DIM*B_DIM)   // 524288
#define TR 64                      // rows per block
#define KS 136                     // xa row stride (shorts): 2-way-free banks, 16B-aligned rows
#define SMS 72                     // smb row stride (shorts)
#define WBLK 512                   // shorts per (grp,plane,ksub) W fragment block (1 KB)
#define BR_STRIDE 147456           // shorts per branch: 18 chunks x 16 blocks x 512

using bf16x8  = __bf16 __attribute__((ext_vector_type(8)));
using short8v = short __attribute__((ext_vector_type(8)));
using f32x16  = float __attribute__((ext_vector_type(16)));

__device__ __forceinline__ float silu_f(float x) {
  return x * __builtin_amdgcn_rcpf(1.0f + __expf(-x));
}

// scalar split (prep only — off critical path)
__device__ __forceinline__ unsigned short bf16_rne(float v) {
  unsigned u = __float_as_uint(v);
  return (unsigned short)((u + 0x7FFFu + ((u >> 16) & 1u)) >> 16);
}
__device__ __forceinline__ void split2(float v, unsigned short& h, unsigned short& l) {
  h = bf16_rne(v);
  float fh = __uint_as_float(((unsigned)h) << 16);
  l = bf16_rne(v - fh);
}

// packed split: 2 floats -> packed bf16 hi pair + packed bf16 lo pair (6 VALU ops)
__device__ __forceinline__ void split2pk(float a, float b, unsigned& hp, unsigned& lp) {
  unsigned h, l;
  asm("v_cvt_pk_bf16_f32 %0, %1, %2" : "=v"(h) : "v"(a), "v"(b));
  float fa = __uint_as_float(h << 16);
  float fb = __uint_as_float(h & 0xffff0000u);
  asm("v_cvt_pk_bf16_f32 %0, %1, %2" : "=v"(l) : "v"(a - fa), "v"(b - fb));
  hp = h; lp = l;
}

// One K=32 chunk with 32x32x16 MFMA.
// A (64 rows) from LDS hi/lo planes; B (wave's 32 cols) from lane-ordered global
// fragment blocks: wl already includes branch base + wave-group + lane*8.
// Block index = cidx*16 + grp*4 + plane*2 + ksub; lane l holds
// col = grp*32+(l&31), k = ksub*16 + (l>>5)*8 + e.
__device__ __forceinline__ void gemm_chunk32(
    const short* __restrict__ xhi, const short* __restrict__ xlo, int xstr,
    int kcol, const short* __restrict__ wl, int cidx,
    f32x16 acc[2], int l31, int l5)
{
  bf16x8 bh[2], bl[2];
  #pragma unroll
  for (int s = 0; s < 2; ++s) {
    bh[s] = __builtin_bit_cast(bf16x8,
              *(const short8v*)(wl + (size_t)(cidx * 16 + s) * WBLK));
    bl[s] = __builtin_bit_cast(bf16x8,
              *(const short8v*)(wl + (size_t)(cidx * 16 + 2 + s) * WBLK));
  }
  #pragma unroll
  for (int rt = 0; rt < 2; ++rt) {
    const short* arow = xhi + (rt * 32 + l31) * xstr + kcol + l5 * 8;
    const short* lrow = xlo + (rt * 32 + l31) * xstr + kcol + l5 * 8;
    #pragma unroll
    for (int s = 0; s < 2; ++s) {
      bf16x8 ah = __builtin_bit_cast(bf16x8, *(const short8v*)(arow + s * 16));
      bf16x8 al = __builtin_bit_cast(bf16x8, *(const short8v*)(lrow + s * 16));
      acc[rt] = __builtin_amdgcn_mfma_f32_32x32x16_bf16(al, bh[s], acc[rt], 0, 0, 0);
      acc[rt] = __builtin_amdgcn_mfma_f32_32x32x16_bf16(ah, bl[s], acc[rt], 0, 0, 0);
      acc[rt] = __builtin_amdgcn_mfma_f32_32x32x16_bf16(ah, bh[s], acc[rt], 0, 0, 0);
    }
  }
}

// Transpose + bf16 hi/lo split of all weights into lane-ordered fragment blocks.
// Per branch: 18 chunk-slots (16 dense = lay*4+kchunk, 2 rbf) x 16 blocks x 512 shorts.
// Element (n,k): cidx = chunk, kk = k&31; block = cidx*16 + (n>>5)*4 + p*2 + (kk>>4);
// within block: lane = (n&31) + 32*((kk>>3)&1), elem = kk&7.
__global__ __launch_bounds__(256) void prep_weights(
    const float* __restrict__ eWin, const float* __restrict__ eWh,
    const float* __restrict__ eWout, const float* __restrict__ erbf,
    const float* __restrict__ fWin, const float* __restrict__ fWh,
    const float* __restrict__ fWout, const float* __restrict__ frbf,
    short* __restrict__ S)
{
  int o = blockIdx.x * 256 + threadIdx.x;
  if (o >= 2 * 73728) return;
  int br = (o >= 73728) ? 1 : 0;
  int r = o - br * 73728;
  short* base = S + br * BR_STRIDE;
  float v; int cidx, n, kk;
  if (r < 65536) {
    int lay = r >> 14, idx = r & 16383;
    n = idx >> 7; int k = idx & 127;
    const float* W = (lay == 0) ? (br ? fWin : eWin)
                   : (lay == 3) ? (br ? fWout : eWout)
                   : ((br ? fWh : eWh) + (lay - 1) * 16384);
    v = W[k * 128 + n];
    cidx = lay * 4 + (k >> 5); kk = k & 31;
  } else {
    int rr = r - 65536;                 // 0..8191
    n = rr >> 6; int k = rr & 63;
    v = (k < NG) ? (br ? frbf : erbf)[k * 128 + n] : 0.0f;
    cidx = 16 + (k >> 5); kk = k & 31;
  }
  int blk = cidx * 16 + (n >> 5) * 4 + (kk >> 4);                    // p = 0
  int idx = blk * WBLK + ((n & 31) + 32 * ((kk >> 3) & 1)) * 8 + (kk & 7);
  unsigned short h, l; split2(v, h, l);
  base[idx] = (short)h;
  base[idx + 2 * WBLK] = (short)l;                                   // p = 1
}

__global__ __launch_bounds__(256, 3) void fused_main(
    const float* __restrict__ T, const float* __restrict__ mask,
    const float* __restrict__ dist,
    const float* __restrict__ ebin, const float* __restrict__ ebh,
    const float* __restrict__ ebout, const float* __restrict__ ehead,
    const float* __restrict__ fbin, const float* __restrict__ fbh,
    const float* __restrict__ fbout, const float* __restrict__ fhead,
    const short* __restrict__ S,
    float* __restrict__ em, float* __restrict__ fm)
{
  __shared__ short xa[2 * TR * KS];     // hi plane, lo plane: 34816 B
  __shared__ float part[4][TR];         // 1024 B  -> 35840 B total

  const int t = threadIdx.x;
  const int wave = t >> 6, lane = t & 63;
  const int l31 = lane & 31, l5 = lane >> 5;
  const int br = blockIdx.x & 1;
  const long tile = blockIdx.x >> 1;
  const long r0g = tile * TR;

  const short* wl = S + br * BR_STRIDE + wave * (4 * WBLK) + lane * 8;
  const float* bin  = br ? fbin : ebin;
  const float* bh_  = br ? fbh : ebh;
  const float* bout = br ? fbout : ebout;
  const float* head = br ? fhead : ehead;
  float* outw = br ? fm : em;

  short* xahi = xa;
  short* xalo = xa + TR * KS;

  // ---- T tile -> xa hi/lo planes (cvt_pk packed split) ----
  {
    int row = t >> 2, seg = t & 3;
    const float* Tp = T + (r0g + row) * E + seg * 32;
    short* ph = xahi + row * KS + seg * 32;
    short* pl = xalo + row * KS + seg * 32;
    #pragma unroll
    for (int j = 0; j < 8; ++j) {
      float4 v = *(const float4*)(Tp + j * 4);
      unsigned h01, l01, h23, l23;
      split2pk(v.x, v.y, h01, l01);
      split2pk(v.z, v.w, h23, l23);
      *(uint2*)(ph + j * 4) = make_uint2(h01, h23);
      *(uint2*)(pl + j * 4) = make_uint2(l01, l23);
    }
  }

  float xres[2][16];
  f32x16 acc[2];

  // ---- 4 dense layers; W fragments stream L2->VGPR, no per-chunk barriers ----
  #pragma unroll 1
  for (int lay = 0; lay < 4; ++lay) {
    const float* bg = (lay == 0) ? bin : (lay == 3) ? bout : (bh_ + (lay - 1) * E);
    float b0 = bg[wave * 32 + l31];
    #pragma unroll
    for (int i = 0; i < 16; ++i) { acc[0][i] = b0; acc[1][i] = b0; }
    __syncthreads();                   // xa writes (stage / prev epilogue) visible
    #pragma unroll
    for (int ch = 0; ch < 4; ++ch)
      gemm_chunk32(xahi, xalo, KS, ch * 32, wl, lay * 4 + ch, acc, l31, l5);
    __syncthreads();                   // all xa reads of this layer done
    if (lay < 3) {
      #pragma unroll
      for (int rt = 0; rt < 2; ++rt)
        #pragma unroll
        for (int rg = 0; rg < 16; rg += 2) {
          float v0 = silu_f(acc[rt][rg]);
          float v1 = silu_f(acc[rt][rg + 1]);
          if (lay > 0) { v0 += xres[rt][rg]; v1 += xres[rt][rg + 1]; }
          xres[rt][rg] = v0; xres[rt][rg + 1] = v1;
          unsigned hp, lp; split2pk(v0, v1, hp, lp);
          int rowa = rt * 32 + 4 * l5 + (rg & 3) + 8 * (rg >> 2);  // rows rowa, rowa+1
          int col = wave * 32 + l31;
          xahi[rowa * KS + col]       = (short)(hp & 0xffffu);
          xahi[(rowa + 1) * KS + col] = (short)(hp >> 16);
          xalo[rowa * KS + col]       = (short)(lp & 0xffffu);
          xalo[(rowa + 1) * KS + col] = (short)(lp >> 16);
        }
    }
  }
  // acc now holds feat (Wout layer, bias included, no activation)

  // ---- smeared gaussians -> smb hi/lo planes (overlay xa; lay3 post-sync covers) ----
  short* smhi = xa;
  short* smlo = xa + TR * SMS;
  const float stepv = 12.0f / 49.0f;
  const float coeff = -0.5f / (stepv * stepv);
  {
    int r = t & 63, kg = t >> 6;
    float d = dist[r0g + r];
    #pragma unroll
    for (int j4 = 0; j4 < 4; ++j4) {
      float vv[4];
      #pragma unroll
      for (int jj = 0; jj < 4; ++jj) {
        int k = kg * 16 + j4 * 4 + jj;
        float dd = d - (float)k * stepv;
        vv[jj] = (k < NG) ? __expf(coeff * dd * dd) : 0.0f;
      }
      unsigned h01, l01, h23, l23;
      split2pk(vv[0], vv[1], h01, l01);
      split2pk(vv[2], vv[3], h23, l23);
      *(uint2*)(smhi + r * SMS + kg * 16 + j4 * 4) = make_uint2(h01, h23);
      *(uint2*)(smlo + r * SMS + kg * 16 + j4 * 4) = make_uint2(l01, l23);
    }
  }
  float h0 = head[wave * 32 + l31];
  f32x16 acc2[2];
  #pragma unroll
  for (int i = 0; i < 16; ++i) { acc2[0][i] = 0.f; acc2[1][i] = 0.f; }
  __syncthreads();                     // smb visible
  gemm_chunk32(smhi, smlo, SMS, 0,  wl, 16, acc2, l31, l5);
  gemm_chunk32(smhi, smlo, SMS, 32, wl, 17, acc2, l31, l5);

  // ---- head dot: reduce over cols (l&31 within each 32-half), cross-wave via LDS ----
  #pragma unroll
  for (int rt = 0; rt < 2; ++rt)
    #pragma unroll
    for (int rg = 0; rg < 16; ++rg) {
      float p = acc[rt][rg] * acc2[rt][rg] * h0;
      p += __shfl_xor(p, 1); p += __shfl_xor(p, 2);
      p += __shfl_xor(p, 4); p += __shfl_xor(p, 8);
      p += __shfl_xor(p, 16);
      if (l31 == 0)
        part[wave][rt * 32 + 4 * l5 + (rg & 3) + 8 * (rg >> 2)] = p;
    }
  __syncthreads();
  if (t < TR) {
    float pr = part[0][t] + part[1][t] + part[2][t] + part[3][t];
    outw[r0g + t] = pr * mask[r0g + t];
  }
}

__global__ __launch_bounds__(256) void energy_kernel(const float* __restrict__ em,
                                                     float* __restrict__ out) {
  __shared__ float red[256];
  int b = blockIdx.x, t = threadIdx.x;
  float s = 0.0f;
  for (int p = t; p < A_DIM * A_DIM; p += 256) s += em[(long)p * B_DIM + b];
  red[t] = s; __syncthreads();
  for (int off = 128; off > 0; off >>= 1) {
    if (t < off) red[t] += red[t + off];
    __syncthreads();
  }
  if (t == 0) out[b] = red[0] * (1.0f / 3600.0f);
}

__global__ __launch_bounds__(256) void forces_kernel(const float* __restrict__ fm,
                                                     const float* __restrict__ vh,
                                                     float* __restrict__ out) {
  int o = blockIdx.x * 256 + threadIdx.x;   // 24576 outputs = [j][b][c]
  if (o >= A_DIM * B_DIM * 3) return;
  int c = o % 3;
  int b = (o / 3) % B_DIM;
  int j = o / (B_DIM * 3);
  float s = 0.0f;
  #pragma unroll 4
  for (int i = 0; i < A_DIM; ++i) {
    long row = ((long)(i * A_DIM + j)) * B_DIM + b;
    s += fm[row] * vh[row * 3 + c];
  }
  out[B_DIM + o] = s * (1.0f / 60.0f);
}

extern "C" void kernel_launch(void* const* d_in, const int* in_sizes, int n_in,
                              void* d_out, int out_size, void* d_ws, size_t ws_size,
                              hipStream_t stream) {
  const float* T    = (const float*)d_in[0];
  const float* mask = (const float*)d_in[1];
  const float* dist = (const float*)d_in[2];
  const float* vh   = (const float*)d_in[3];
  const float* eWin = (const float*)d_in[4];
  const float* ebin = (const float*)d_in[5];
  const float* eWh  = (const float*)d_in[6];
  const float* ebh  = (const float*)d_in[7];
  const float* eWout= (const float*)d_in[8];
  const float* ebout= (const float*)d_in[9];
  const float* erbf = (const float*)d_in[10];
  const float* ehead= (const float*)d_in[11];
  const float* fWin = (const float*)d_in[12];
  const float* fbin = (const float*)d_in[13];
  const float* fWh  = (const float*)d_in[14];
  const float* fbh  = (const float*)d_in[15];
  const float* fWout= (const float*)d_in[16];
  const float* fbout= (const float*)d_in[17];
  const float* frbf = (const float*)d_in[18];
  const float* fhead= (const float*)d_in[19];

  float* em = (float*)d_ws;
  float* fm = em + NROW;
  short* S  = (short*)(fm + NROW);          // 4 MB + 576 KB used of d_ws
  float* out = (float*)d_out;

  prep_weights<<<576, 256, 0, stream>>>(eWin, eWh, eWout, erbf,
                                        fWin, fWh, fWout, frbf, S);
  fused_main<<<2 * (NROW / TR), 256, 0, stream>>>(
      T, mask, dist,
      ebin, ebh, ebout, ehead,
      fbin, fbh, fbout, fhead,
      S, em, fm);
  energy_kernel<<<B_DIM, 256, 0, stream>>>(em, out);
  forces_kernel<<<(A_DIM * B_DIM * 3) / 256, 256, 0, stream>>>(fm, vh, out);
}